// Round 6
// baseline (317.207 us; speedup 1.0000x reference)
//
#include <hip/hip_runtime.h>

#define NN   6144
#define EE   98304
#define DIN  128
#define DD   256
#define TT   32
#define NH   4
#define ATTN_Z 6
#define WROWS 3328   // 256 wcat + 2*(768+256+256+256)

typedef __attribute__((ext_vector_type(8))) short short8;
typedef __attribute__((ext_vector_type(4))) float f32x4;

__device__ __forceinline__ unsigned short f2bf(float f) {
    unsigned u = __float_as_uint(f);
    return (unsigned short)((u + 0x7fffu + ((u >> 16) & 1u)) >> 16);
}
__device__ __forceinline__ unsigned pk2(float a, float b) {
    return (unsigned)f2bf(a) | ((unsigned)f2bf(b) << 16);
}
__device__ __forceinline__ short8 pack8(float4 a, float4 b, float s) {
    union { unsigned u[4]; short8 v; } r;
    r.u[0] = pk2(a.x * s, a.y * s);
    r.u[1] = pk2(a.z * s, a.w * s);
    r.u[2] = pk2(b.x * s, b.y * s);
    r.u[3] = pk2(b.z * s, b.w * s);
    return r.v;
}

// ---------------- CSR build: histogram ----------------
__global__ void aml_hist_k(const int* __restrict__ ei, int* __restrict__ deg) {
    int e = blockIdx.x * 256 + threadIdx.x;
    if (e < EE) atomicAdd(&deg[ei[EE + e]], 1);
}

// ---------------- CSR build: exclusive scan (one block, 256 x 24) ----------------
__global__ void aml_scan_k(const int* __restrict__ deg, int* __restrict__ rowptr,
                           int* __restrict__ cursor) {
    int t = threadIdx.x;
    int base = t * 24;
    int loc[24];
    int s = 0;
    #pragma unroll
    for (int j = 0; j < 24; ++j) { loc[j] = s; s += deg[base + j]; }
    __shared__ int part[256];
    part[t] = s;
    __syncthreads();
    for (int o = 1; o < 256; o <<= 1) {
        int v = (t >= o) ? part[t - o] : 0;
        __syncthreads();
        part[t] += v;
        __syncthreads();
    }
    int off = (t > 0) ? part[t - 1] : 0;
    #pragma unroll
    for (int j = 0; j < 24; ++j) {
        rowptr[base + j] = off + loc[j];
        cursor[base + j] = off + loc[j];
    }
    if (t == 255) rowptr[NN] = part[255];
}

// ---------------- CSR build: scatter edge sources ----------------
__global__ void aml_scatter2_k(const int* __restrict__ ei, int* __restrict__ cursor,
                               int* __restrict__ eid) {
    int e = blockIdx.x * 256 + threadIdx.x;
    if (e >= EE) return;
    int slot = atomicAdd(&cursor[ei[EE + e]], 1);
    eid[slot] = ei[e];
}

// ---------------- gather-mean + concat: ac[i] = [mean_{j->i} x_j | x_i] ----------------
__global__ void aml_gather_k(const float* __restrict__ x, const int* __restrict__ rowptr,
                             const int* __restrict__ eid, float* __restrict__ ac) {
    int node = blockIdx.x * 4 + (threadIdx.x >> 6);
    int lane = threadIdx.x & 63;
    int p0 = rowptr[node], p1 = rowptr[node + 1];
    float ax = 0.f, ay = 0.f;
    int j = p0;
    for (; j + 1 < p1; j += 2) {
        int s0 = eid[j], s1 = eid[j + 1];
        float2 v0 = *(const float2*)(x + (size_t)s0 * DIN + lane * 2);
        float2 v1 = *(const float2*)(x + (size_t)s1 * DIN + lane * 2);
        ax += v0.x + v1.x; ay += v0.y + v1.y;
    }
    if (j < p1) {
        float2 v = *(const float2*)(x + (size_t)eid[j] * DIN + lane * 2);
        ax += v.x; ay += v.y;
    }
    float inv = 1.0f / fmaxf((float)(p1 - p0), 1.0f);
    float2 xr = *(const float2*)(x + (size_t)node * DIN + lane * 2);
    float2 mv = { ax * inv, ay * inv };
    *(float2*)(ac + (size_t)node * DD + lane * 2) = mv;
    *(float2*)(ac + (size_t)node * DD + DIN + lane * 2) = xr;
}

// ---------------- prep: all weights -> bf16 rows [WROWS][256]; + segment offsets ----------------
__global__ void aml_prep_k(const float* __restrict__ lin_l_w, const float* __restrict__ lin_r_w,
                           const float* __restrict__ inp_w, const float* __restrict__ out_w,
                           const float* __restrict__ ff1_w, const float* __restrict__ ff2_w,
                           const int* __restrict__ ts, unsigned short* __restrict__ wb,
                           int* __restrict__ offs) {
    int r = blockIdx.x;
    if (r == WROWS) {
        int t = threadIdx.x;
        if (t <= TT) {
            int lo = 0, hi = NN;
            while (lo < hi) { int mid = (lo + hi) >> 1; if (ts[mid] < t) lo = mid + 1; else hi = mid; }
            offs[t] = lo;
        }
        return;
    }
    int k = threadIdx.x;
    float v;
    if (r < 256) {
        v = (k < DIN) ? lin_l_w[r * DIN + k] : lin_r_w[r * DIN + (k - DIN)];
    } else {
        int r2 = r - 256;
        int l = r2 / 1536, r3 = r2 % 1536;
        const float* src; int rr;
        if (r3 < 768)       { src = inp_w + (size_t)l * 768 * DD; rr = r3; }
        else if (r3 < 1024) { src = out_w + (size_t)l * DD * DD;  rr = r3 - 768; }
        else if (r3 < 1280) { src = ff1_w + (size_t)l * DD * DD;  rr = r3 - 1024; }
        else                { src = ff2_w + (size_t)l * DD * DD;  rr = r3 - 1280; }
        v = src[(size_t)rr * DD + k];
    }
    wb[(size_t)r * DD + k] = f2bf(v);
}

// ---------------- streaming MFMA GEMM: 1 wave, 16 rows x 256 cols, K=256 ----------------
// MODE 0: +bias. MODE 1: +bias, ReLU. MODE 2: +bias +residual(C) + LayerNorm -> C.
template <int MODE>
__global__ __launch_bounds__(64)
void aml_gemm2_k(const float* __restrict__ A, const unsigned short* __restrict__ Wb,
                 const float* __restrict__ bias, float* __restrict__ C, int Mout,
                 const float* __restrict__ g, const float* __restrict__ bv) {
    const int lane = threadIdx.x;
    const int lrow = lane & 15, lk = lane >> 4;
    const int row0 = blockIdx.x * 16;
    const int colb = blockIdx.y * 256;
    const float* ap = A + (size_t)(row0 + lrow) * 256;

    f32x4 acc[16] = {};
    #pragma unroll
    for (int ks = 0; ks < 8; ++ks) {
        int k0 = ks * 32 + lk * 8;
        float4 a0 = *(const float4*)(ap + k0);
        float4 a1 = *(const float4*)(ap + k0 + 4);
        short8 af = pack8(a0, a1, 1.0f);
        #pragma unroll
        for (int ct = 0; ct < 16; ++ct) {
            int wrow = colb + ct * 16 + lrow;
            short8 bf = *(const short8*)(Wb + (size_t)wrow * 256 + k0);
            acc[ct] = __builtin_amdgcn_mfma_f32_16x16x32_bf16(af, bf, acc[ct], 0, 0, 0);
        }
    }

    if (MODE < 2) {
        #pragma unroll
        for (int ct = 0; ct < 16; ++ct) {
            int col = colb + ct * 16 + lrow;
            float bvv = bias[col];
            #pragma unroll
            for (int r = 0; r < 4; ++r) {
                int grow = row0 + lk * 4 + r;
                float v = acc[ct][r] + bvv;
                if (MODE == 1) v = fmaxf(v, 0.0f);
                C[(size_t)grow * Mout + col] = v;
            }
        }
    } else {
        // bias + residual, accumulate row stats
        float s[4] = {}, q[4] = {};
        #pragma unroll
        for (int ct = 0; ct < 16; ++ct) {
            int col = colb + ct * 16 + lrow;
            float bvv = bias[col];
            #pragma unroll
            for (int r = 0; r < 4; ++r) {
                int grow = row0 + lk * 4 + r;
                float v = acc[ct][r] + bvv + C[(size_t)grow * 256 + col];
                acc[ct][r] = v;
                s[r] += v;
                q[r] += v * v;
            }
        }
        #pragma unroll
        for (int off = 1; off < 16; off <<= 1) {
            #pragma unroll
            for (int r = 0; r < 4; ++r) {
                s[r] += __shfl_xor(s[r], off);
                q[r] += __shfl_xor(q[r], off);
            }
        }
        float mu[4], iv[4];
        #pragma unroll
        for (int r = 0; r < 4; ++r) {
            mu[r] = s[r] * (1.0f / 256.0f);
            iv[r] = rsqrtf(q[r] * (1.0f / 256.0f) - mu[r] * mu[r] + 1e-5f);
        }
        #pragma unroll
        for (int ct = 0; ct < 16; ++ct) {
            int col = colb + ct * 16 + lrow;
            float gv = g[col], bb = bv[col];
            #pragma unroll
            for (int r = 0; r < 4; ++r) {
                int grow = row0 + lk * 4 + r;
                C[(size_t)grow * 256 + col] = (acc[ct][r] - mu[r]) * iv[r] * gv + bb;
            }
        }
    }
}

// ---------------- BatchNorm stats: coalesced rows, atomic partials ----------------
__global__ void aml_bn_stats_k(const float* __restrict__ h, float* __restrict__ stats) {
    int d = threadIdx.x;
    int r0 = blockIdx.x * 96;
    float s = 0.f, ss = 0.f;
    for (int i = 0; i < 96; ++i) {
        float v = h[(size_t)(r0 + i) * DD + d];
        s += v; ss += v * v;
    }
    atomicAdd(&stats[d], s);
    atomicAdd(&stats[DD + d], ss);
}

__global__ void aml_bn_apply_k(float* __restrict__ h, const float* __restrict__ stats,
                               const float* __restrict__ g, const float* __restrict__ b) {
    int idx = blockIdx.x * 256 + threadIdx.x;
    int d = idx & (DD - 1);
    float mu = stats[d] * (1.0f / NN);
    float var = stats[DD + d] * (1.0f / NN) - mu * mu;
    float v = (h[idx] - mu) * rsqrtf(var + 1e-5f) * g[d] + b[d];
    h[idx] = fmaxf(v, 0.0f);
}

// ---------------- MFMA flash attention over block-diagonal segments ----------------
__global__ __launch_bounds__(256)
void aml_attn_k(const float* __restrict__ qkv, const int* __restrict__ offs,
                float* __restrict__ o) {
    int tb = blockIdx.x, head = blockIdx.y, z = blockIdx.z;
    int start = offs[tb], end = offs[tb + 1];
    int S = end - start;
    if (S <= z * 64) return;
    int t = threadIdx.x, wave = t >> 6, lane = t & 63;
    int lq = lane & 15, lk = lane >> 4;
    int qoff = head * 64;

    __shared__ __align__(16) unsigned char Kl[8192];
    __shared__ __align__(16) unsigned char Vt[8192];
    __shared__ __align__(16) unsigned char Pl[4][2048];
    __shared__ float Ol[4][16][65];

    int qi = start + z * 64 + wave * 16 + lq;
    int qic = min(qi, end - 1);
    const float* qp = qkv + (size_t)qic * 768 + qoff + lk * 8;
    short8 qf[2];
    #pragma unroll
    for (int ks = 0; ks < 2; ++ks) {
        float4 a = *(const float4*)(qp + ks * 32);
        float4 b = *(const float4*)(qp + ks * 32 + 4);
        qf[ks] = pack8(a, b, 0.125f);
    }

    float m = -1e30f, l = 0.f;
    f32x4 acc[4] = {};

    int ntile = (S + 63) >> 6;
    for (int tile = 0; tile < ntile; ++tile) {
        int jcnt = S - tile * 64; if (jcnt > 64) jcnt = 64;
        {
            int j = t >> 2, d0 = (t & 3) * 16;
            unsigned char* krow = Kl + j * 128;
            if (j < jcnt) {
                const float* kp = qkv + (size_t)(start + tile * 64 + j) * 768 + 256 + qoff + d0;
                float4 k0 = *(const float4*)kp, k1 = *(const float4*)(kp + 4);
                float4 k2 = *(const float4*)(kp + 8), k3 = *(const float4*)(kp + 12);
                uint4 pc0 = { pk2(k0.x, k0.y), pk2(k0.z, k0.w), pk2(k1.x, k1.y), pk2(k1.z, k1.w) };
                uint4 pc1 = { pk2(k2.x, k2.y), pk2(k2.z, k2.w), pk2(k3.x, k3.y), pk2(k3.z, k3.w) };
                *(uint4*)(krow + ((d0 * 2) ^ ((j & 7) << 4))) = pc0;
                *(uint4*)(krow + ((d0 * 2 + 16) ^ ((j & 7) << 4))) = pc1;
                const float* vp = kp + 256;
                float4 v0 = *(const float4*)vp, v1 = *(const float4*)(vp + 4);
                float4 v2 = *(const float4*)(vp + 8), v3 = *(const float4*)(vp + 12);
                float vv[16] = { v0.x, v0.y, v0.z, v0.w, v1.x, v1.y, v1.z, v1.w,
                                 v2.x, v2.y, v2.z, v2.w, v3.x, v3.y, v3.z, v3.w };
                #pragma unroll
                for (int i = 0; i < 16; ++i) {
                    int d = d0 + i;
                    *(unsigned short*)(Vt + d * 128 + ((j * 2) ^ ((d & 7) << 4))) = f2bf(vv[i]);
                }
            } else {
                uint4 zz = { 0, 0, 0, 0 };
                *(uint4*)(krow + ((d0 * 2) ^ ((j & 7) << 4))) = zz;
                *(uint4*)(krow + ((d0 * 2 + 16) ^ ((j & 7) << 4))) = zz;
                #pragma unroll
                for (int i = 0; i < 16; ++i) {
                    int d = d0 + i;
                    *(unsigned short*)(Vt + d * 128 + ((j * 2) ^ ((d & 7) << 4))) = 0;
                }
            }
        }
        __syncthreads();

        f32x4 sv[4];
        #pragma unroll
        for (int kt = 0; kt < 4; ++kt) {
            int kr = kt * 16 + lq;
            f32x4 s = {};
            #pragma unroll
            for (int ks = 0; ks < 2; ++ks) {
                short8 kf = *(const short8*)(Kl + kr * 128 + ((ks * 64 + lk * 16) ^ ((kr & 7) << 4)));
                s = __builtin_amdgcn_mfma_f32_16x16x32_bf16(kf, qf[ks], s, 0, 0, 0);
            }
            sv[kt] = s;
        }
        float pm = -1e30f;
        #pragma unroll
        for (int kt = 0; kt < 4; ++kt) {
            #pragma unroll
            for (int r = 0; r < 4; ++r) {
                int kk = tile * 64 + kt * 16 + lk * 4 + r;
                float s = (kk < S) ? sv[kt][r] : -1e30f;
                sv[kt][r] = s;
                pm = fmaxf(pm, s);
            }
        }
        pm = fmaxf(pm, __shfl_xor(pm, 16));
        pm = fmaxf(pm, __shfl_xor(pm, 32));
        float mn = fmaxf(m, pm);
        float corr = __expf(m - mn);
        m = mn;
        float ps = 0.f;
        #pragma unroll
        for (int kt = 0; kt < 4; ++kt) {
            #pragma unroll
            for (int r = 0; r < 4; ++r) {
                float p = __expf(sv[kt][r] - mn);
                sv[kt][r] = p;
                ps += p;
            }
            uint2 w = { pk2(sv[kt][0], sv[kt][1]), pk2(sv[kt][2], sv[kt][3]) };
            *(uint2*)(Pl[wave] + lq * 128 + ((kt * 32 + lk * 8) ^ ((lq & 7) << 4))) = w;
        }
        ps += __shfl_xor(ps, 16);
        ps += __shfl_xor(ps, 32);
        l = l * corr + ps;
        #pragma unroll
        for (int dt = 0; dt < 4; ++dt) {
            #pragma unroll
            for (int r = 0; r < 4; ++r) acc[dt][r] *= corr;
        }
        #pragma unroll
        for (int ks = 0; ks < 2; ++ks) {
            short8 pf = *(const short8*)(Pl[wave] + lq * 128 + ((ks * 64 + lk * 16) ^ ((lq & 7) << 4)));
            #pragma unroll
            for (int dt = 0; dt < 4; ++dt) {
                int dr = dt * 16 + lq;
                short8 vf = *(const short8*)(Vt + dr * 128 + ((ks * 64 + lk * 16) ^ ((dr & 7) << 4)));
                acc[dt] = __builtin_amdgcn_mfma_f32_16x16x32_bf16(vf, pf, acc[dt], 0, 0, 0);
            }
        }
        __syncthreads();
    }

    float linv = 1.0f / l;
    #pragma unroll
    for (int dt = 0; dt < 4; ++dt) {
        #pragma unroll
        for (int r = 0; r < 4; ++r)
            Ol[wave][lq][dt * 16 + lk * 4 + r] = acc[dt][r] * linv;
    }
    int q2 = lane >> 2, c2 = lane & 3;
    int qg = start + z * 64 + wave * 16 + q2;
    if (qg < end) {
        float* op = o + (size_t)qg * DD + qoff + c2 * 16;
        const float* sp = &Ol[wave][q2][c2 * 16];
        #pragma unroll
        for (int i = 0; i < 4; ++i) ((float4*)op)[i] = *(const float4*)(sp + i * 4);
    }
}

// ---------------- classifier: wave per row ----------------
__global__ void aml_cls_k(const float* __restrict__ h, const float* __restrict__ w,
                          const float* __restrict__ b, float* __restrict__ out) {
    int row = blockIdx.x * 4 + (threadIdx.x >> 6);
    int lane = threadIdx.x & 63;
    float4 v = *(const float4*)(h + (size_t)row * DD + lane * 4);
    float4 w0 = *(const float4*)(w + lane * 4);
    float4 w1 = *(const float4*)(w + DD + lane * 4);
    float a0 = v.x * w0.x + v.y * w0.y + v.z * w0.z + v.w * w0.w;
    float a1 = v.x * w1.x + v.y * w1.y + v.z * w1.z + v.w * w1.w;
    #pragma unroll
    for (int off = 32; off; off >>= 1) {
        a0 += __shfl_xor(a0, off);
        a1 += __shfl_xor(a1, off);
    }
    if (lane == 0) {
        out[row * 2]     = a0 + b[0];
        out[row * 2 + 1] = a1 + b[1];
    }
}

extern "C" void kernel_launch(void* const* d_in, const int* in_sizes, int n_in,
                              void* d_out, int out_size, void* d_ws, size_t ws_size,
                              hipStream_t stream) {
    const float* x       = (const float*)d_in[0];
    const int*   ei      = (const int*)d_in[1];
    const int*   ts      = (const int*)d_in[2];
    const float* lin_l_w = (const float*)d_in[3];
    const float* lin_l_b = (const float*)d_in[4];
    const float* lin_r_w = (const float*)d_in[5];
    const float* bn_g    = (const float*)d_in[6];
    const float* bn_b    = (const float*)d_in[7];
    const float* inp_w   = (const float*)d_in[8];
    const float* inp_b   = (const float*)d_in[9];
    const float* out_w   = (const float*)d_in[10];
    const float* out_b   = (const float*)d_in[11];
    const float* ff1_w   = (const float*)d_in[12];
    const float* ff1_b   = (const float*)d_in[13];
    const float* ff2_w   = (const float*)d_in[14];
    const float* ff2_b   = (const float*)d_in[15];
    const float* ln1_g   = (const float*)d_in[16];
    const float* ln1_b   = (const float*)d_in[17];
    const float* ln2_g   = (const float*)d_in[18];
    const float* ln2_b   = (const float*)d_in[19];
    const float* cls_w   = (const float*)d_in[20];
    const float* cls_b   = (const float*)d_in[21];

    float* ws     = (float*)d_ws;
    float* stats  = ws;                          // 512 f32 (zeroed)
    int*   deg    = (int*)(stats + 512);         // NN (zeroed)
    int*   rowptr = deg + NN;                    // NN+4 (padded, keeps 16B alignment)
    int*   cursor = rowptr + NN + 4;             // NN
    int*   eid    = cursor + NN;                 // EE
    int*   offs   = eid + EE;                    // 64
    unsigned short* wb = (unsigned short*)(offs + 64);  // WROWS*256 bf16
    float* h      = (float*)(wb + (size_t)WROWS * 256); // N*256
    float* qkv    = h + (size_t)NN * DD;         // N*768
    float* t1     = qkv + (size_t)NN * 768;      // N*256
    float* ac     = qkv;                         // alias (consumed before qkv written)

    // bf16 weight block offsets (rows)
    const unsigned short* wb_cat = wb;
    const unsigned short* wb_inp[2] = { wb + (size_t)(256) * 256,
                                        wb + (size_t)(256 + 1536) * 256 };
    const unsigned short* wb_out[2] = { wb + (size_t)(256 + 768) * 256,
                                        wb + (size_t)(256 + 1536 + 768) * 256 };
    const unsigned short* wb_ff1[2] = { wb + (size_t)(256 + 1024) * 256,
                                        wb + (size_t)(256 + 1536 + 1024) * 256 };
    const unsigned short* wb_ff2[2] = { wb + (size_t)(256 + 1280) * 256,
                                        wb + (size_t)(256 + 1536 + 1280) * 256 };

    hipMemsetAsync(stats, 0, 512 * sizeof(float) + NN * sizeof(int), stream);

    aml_hist_k<<<EE / 256, 256, 0, stream>>>(ei, deg);
    aml_scan_k<<<1, 256, 0, stream>>>(deg, rowptr, cursor);
    aml_scatter2_k<<<EE / 256, 256, 0, stream>>>(ei, cursor, eid);
    aml_gather_k<<<NN / 4, 256, 0, stream>>>(x, rowptr, eid, ac);
    aml_prep_k<<<WROWS + 1, 256, 0, stream>>>(lin_l_w, lin_r_w, inp_w, out_w, ff1_w, ff2_w,
                                              ts, wb, offs);
    aml_gemm2_k<0><<<dim3(NN / 16, 1), 64, 0, stream>>>(ac, wb_cat, lin_l_b, h, DD, nullptr, nullptr);
    aml_bn_stats_k<<<64, 256, 0, stream>>>(h, stats);
    aml_bn_apply_k<<<(NN * DD) / 256, 256, 0, stream>>>(h, stats, bn_g, bn_b);

    for (int l = 0; l < 2; ++l) {
        aml_gemm2_k<0><<<dim3(NN / 16, 3), 64, 0, stream>>>(h, wb_inp[l], inp_b + (size_t)l * 768,
                                                            qkv, 768, nullptr, nullptr);
        aml_attn_k<<<dim3(TT, NH, ATTN_Z), 256, 0, stream>>>(qkv, offs, t1);
        aml_gemm2_k<2><<<dim3(NN / 16, 1), 64, 0, stream>>>(t1, wb_out[l], out_b + (size_t)l * DD,
                                                            h, DD, ln1_g + (size_t)l * DD,
                                                            ln1_b + (size_t)l * DD);
        aml_gemm2_k<1><<<dim3(NN / 16, 1), 64, 0, stream>>>(h, wb_ff1[l], ff1_b + (size_t)l * DD,
                                                            t1, DD, nullptr, nullptr);
        aml_gemm2_k<2><<<dim3(NN / 16, 1), 64, 0, stream>>>(t1, wb_ff2[l], ff2_b + (size_t)l * DD,
                                                            h, DD, ln2_g + (size_t)l * DD,
                                                            ln2_b + (size_t)l * DD);
    }

    aml_cls_k<<<NN / 4, 256, 0, stream>>>(h, cls_w, cls_b, (float*)d_out);
}

// Round 7
// 257.475 us; speedup vs baseline: 1.2320x; 1.2320x over previous
//
#include <hip/hip_runtime.h>

#define NN   6144
#define EE   98304
#define DIN  128
#define DD   256
#define TT   32
#define NH   4
#define ATTN_Z 6
#define WROWS 3328   // 256 wcat + 2*(768+256+256+256)

typedef __attribute__((ext_vector_type(8))) short short8;
typedef __attribute__((ext_vector_type(4))) float f32x4;

__device__ __forceinline__ unsigned short f2bf(float f) {
    unsigned u = __float_as_uint(f);
    return (unsigned short)((u + 0x7fffu + ((u >> 16) & 1u)) >> 16);
}
__device__ __forceinline__ unsigned pk2(float a, float b) {
    return (unsigned)f2bf(a) | ((unsigned)f2bf(b) << 16);
}
__device__ __forceinline__ short8 pack8(float4 a, float4 b, float s) {
    union { unsigned u[4]; short8 v; } r;
    r.u[0] = pk2(a.x * s, a.y * s);
    r.u[1] = pk2(a.z * s, a.w * s);
    r.u[2] = pk2(b.x * s, b.y * s);
    r.u[3] = pk2(b.z * s, b.w * s);
    return r.v;
}

// ---------------- CSR build: histogram ----------------
__global__ void aml_hist_k(const int* __restrict__ ei, int* __restrict__ deg) {
    int e = blockIdx.x * 256 + threadIdx.x;
    if (e < EE) atomicAdd(&deg[ei[EE + e]], 1);
}

// ---------------- CSR build: exclusive scan (one block, 256 x 24) ----------------
__global__ void aml_scan_k(const int* __restrict__ deg, int* __restrict__ rowptr,
                           int* __restrict__ cursor) {
    int t = threadIdx.x;
    int base = t * 24;
    int loc[24];
    int s = 0;
    #pragma unroll
    for (int j = 0; j < 24; ++j) { loc[j] = s; s += deg[base + j]; }
    __shared__ int part[256];
    part[t] = s;
    __syncthreads();
    for (int o = 1; o < 256; o <<= 1) {
        int v = (t >= o) ? part[t - o] : 0;
        __syncthreads();
        part[t] += v;
        __syncthreads();
    }
    int off = (t > 0) ? part[t - 1] : 0;
    #pragma unroll
    for (int j = 0; j < 24; ++j) {
        rowptr[base + j] = off + loc[j];
        cursor[base + j] = off + loc[j];
    }
    if (t == 255) rowptr[NN] = part[255];
}

// ---------------- CSR build: scatter edge sources ----------------
__global__ void aml_scatter2_k(const int* __restrict__ ei, int* __restrict__ cursor,
                               int* __restrict__ eid) {
    int e = blockIdx.x * 256 + threadIdx.x;
    if (e >= EE) return;
    int slot = atomicAdd(&cursor[ei[EE + e]], 1);
    eid[slot] = ei[e];
}

// ---------------- gather-mean + concat: ac[i] = [mean_{j->i} x_j | x_i] ----------------
__global__ void aml_gather_k(const float* __restrict__ x, const int* __restrict__ rowptr,
                             const int* __restrict__ eid, float* __restrict__ ac) {
    int node = blockIdx.x * 4 + (threadIdx.x >> 6);
    int lane = threadIdx.x & 63;
    int p0 = rowptr[node], p1 = rowptr[node + 1];
    float ax = 0.f, ay = 0.f;
    int j = p0;
    for (; j + 1 < p1; j += 2) {
        int s0 = eid[j], s1 = eid[j + 1];
        float2 v0 = *(const float2*)(x + (size_t)s0 * DIN + lane * 2);
        float2 v1 = *(const float2*)(x + (size_t)s1 * DIN + lane * 2);
        ax += v0.x + v1.x; ay += v0.y + v1.y;
    }
    if (j < p1) {
        float2 v = *(const float2*)(x + (size_t)eid[j] * DIN + lane * 2);
        ax += v.x; ay += v.y;
    }
    float inv = 1.0f / fmaxf((float)(p1 - p0), 1.0f);
    float2 xr = *(const float2*)(x + (size_t)node * DIN + lane * 2);
    float2 mv = { ax * inv, ay * inv };
    *(float2*)(ac + (size_t)node * DD + lane * 2) = mv;
    *(float2*)(ac + (size_t)node * DD + DIN + lane * 2) = xr;
}

// ---------------- prep: all weights -> bf16 rows [WROWS][256]; + segment offsets ----------------
__global__ void aml_prep_k(const float* __restrict__ lin_l_w, const float* __restrict__ lin_r_w,
                           const float* __restrict__ inp_w, const float* __restrict__ out_w,
                           const float* __restrict__ ff1_w, const float* __restrict__ ff2_w,
                           const int* __restrict__ ts, unsigned short* __restrict__ wb,
                           int* __restrict__ offs) {
    int r = blockIdx.x;
    if (r == WROWS) {
        int t = threadIdx.x;
        if (t <= TT) {
            int lo = 0, hi = NN;
            while (lo < hi) { int mid = (lo + hi) >> 1; if (ts[mid] < t) lo = mid + 1; else hi = mid; }
            offs[t] = lo;
        }
        return;
    }
    int k = threadIdx.x;
    float v;
    if (r < 256) {
        v = (k < DIN) ? lin_l_w[r * DIN + k] : lin_r_w[r * DIN + (k - DIN)];
    } else {
        int r2 = r - 256;
        int l = r2 / 1536, r3 = r2 % 1536;
        const float* src; int rr;
        if (r3 < 768)       { src = inp_w + (size_t)l * 768 * DD; rr = r3; }
        else if (r3 < 1024) { src = out_w + (size_t)l * DD * DD;  rr = r3 - 768; }
        else if (r3 < 1280) { src = ff1_w + (size_t)l * DD * DD;  rr = r3 - 1024; }
        else                { src = ff2_w + (size_t)l * DD * DD;  rr = r3 - 1280; }
        v = src[(size_t)rr * DD + k];
    }
    wb[(size_t)r * DD + k] = f2bf(v);
}

// ---------------- streaming MFMA GEMM v3: 4-wave block, 16 rows, col-split ----------------
// wave w covers cols [colb + w*64, +64). MODE 0: +bias. MODE 1: +bias+ReLU.
// MODE 2: +bias +residual(C) + LayerNorm (cross-wave LDS reduce) -> C (Mout must be 256).
template <int MODE>
__global__ __launch_bounds__(256)
void aml_gemm3_k(const float* __restrict__ A, const unsigned short* __restrict__ Wb,
                 const float* __restrict__ bias, float* __restrict__ C, int Mout,
                 const float* __restrict__ g, const float* __restrict__ bv) {
    const int t = threadIdx.x;
    const int wave = t >> 6, lane = t & 63;
    const int lrow = lane & 15, lk = lane >> 4;
    const int row0 = blockIdx.x * 16;
    const int wcol = blockIdx.y * 256 + wave * 64;
    const float* ap = A + (size_t)(row0 + lrow) * 256;

    f32x4 acc[4] = {};
    #pragma unroll
    for (int ks = 0; ks < 8; ++ks) {
        int k0 = ks * 32 + lk * 8;
        float4 a0 = *(const float4*)(ap + k0);
        float4 a1 = *(const float4*)(ap + k0 + 4);
        short8 af = pack8(a0, a1, 1.0f);
        #pragma unroll
        for (int ct = 0; ct < 4; ++ct) {
            int wrow = wcol + ct * 16 + lrow;
            short8 bf = *(const short8*)(Wb + (size_t)wrow * 256 + k0);
            acc[ct] = __builtin_amdgcn_mfma_f32_16x16x32_bf16(af, bf, acc[ct], 0, 0, 0);
        }
    }

    if (MODE < 2) {
        #pragma unroll
        for (int ct = 0; ct < 4; ++ct) {
            int col = wcol + ct * 16 + lrow;
            float bvv = bias[col];
            #pragma unroll
            for (int r = 0; r < 4; ++r) {
                int grow = row0 + lk * 4 + r;
                float v = acc[ct][r] + bvv;
                if (MODE == 1) v = fmaxf(v, 0.0f);
                C[(size_t)grow * Mout + col] = v;
            }
        }
    } else {
        float s[4] = {}, q[4] = {};
        #pragma unroll
        for (int ct = 0; ct < 4; ++ct) {
            int col = wcol + ct * 16 + lrow;
            float bvv = bias[col];
            #pragma unroll
            for (int r = 0; r < 4; ++r) {
                int grow = row0 + lk * 4 + r;
                float v = acc[ct][r] + bvv + C[(size_t)grow * 256 + col];
                acc[ct][r] = v;
                s[r] += v; q[r] += v * v;
            }
        }
        #pragma unroll
        for (int off = 1; off < 16; off <<= 1) {
            #pragma unroll
            for (int r = 0; r < 4; ++r) {
                s[r] += __shfl_xor(s[r], off);
                q[r] += __shfl_xor(q[r], off);
            }
        }
        __shared__ float reds[4][16], redq[4][16];
        if (lrow == 0) {
            #pragma unroll
            for (int r = 0; r < 4; ++r) {
                reds[wave][lk * 4 + r] = s[r];
                redq[wave][lk * 4 + r] = q[r];
            }
        }
        __syncthreads();
        float mu[4], iv[4];
        #pragma unroll
        for (int r = 0; r < 4; ++r) {
            int rr = lk * 4 + r;
            float S = reds[0][rr] + reds[1][rr] + reds[2][rr] + reds[3][rr];
            float Q = redq[0][rr] + redq[1][rr] + redq[2][rr] + redq[3][rr];
            mu[r] = S * (1.0f / 256.0f);
            iv[r] = rsqrtf(Q * (1.0f / 256.0f) - mu[r] * mu[r] + 1e-5f);
        }
        #pragma unroll
        for (int ct = 0; ct < 4; ++ct) {
            int col = wcol + ct * 16 + lrow;
            float gv = g[col], bb = bv[col];
            #pragma unroll
            for (int r = 0; r < 4; ++r) {
                int grow = row0 + lk * 4 + r;
                C[(size_t)grow * 256 + col] = (acc[ct][r] - mu[r]) * iv[r] * gv + bb;
            }
        }
    }
}

// ---------------- BatchNorm stats: coalesced rows, atomic partials ----------------
__global__ void aml_bn_stats_k(const float* __restrict__ h, float* __restrict__ stats) {
    int d = threadIdx.x;
    int r0 = blockIdx.x * 96;
    float s = 0.f, ss = 0.f;
    for (int i = 0; i < 96; ++i) {
        float v = h[(size_t)(r0 + i) * DD + d];
        s += v; ss += v * v;
    }
    atomicAdd(&stats[d], s);
    atomicAdd(&stats[DD + d], ss);
}

__global__ void aml_bn_apply_k(float* __restrict__ h, const float* __restrict__ stats,
                               const float* __restrict__ g, const float* __restrict__ b) {
    int idx = blockIdx.x * 256 + threadIdx.x;
    int d = idx & (DD - 1);
    float mu = stats[d] * (1.0f / NN);
    float var = stats[DD + d] * (1.0f / NN) - mu * mu;
    float v = (h[idx] - mu) * rsqrtf(var + 1e-5f) * g[d] + b[d];
    h[idx] = fmaxf(v, 0.0f);
}

// ---------------- MFMA flash attention over block-diagonal segments ----------------
__global__ __launch_bounds__(256)
void aml_attn_k(const float* __restrict__ qkv, const int* __restrict__ offs,
                float* __restrict__ o) {
    int tb = blockIdx.x, head = blockIdx.y, z = blockIdx.z;
    int start = offs[tb], end = offs[tb + 1];
    int S = end - start;
    if (S <= z * 64) return;
    int t = threadIdx.x, wave = t >> 6, lane = t & 63;
    int lq = lane & 15, lk = lane >> 4;
    int qoff = head * 64;

    __shared__ __align__(16) unsigned char Kl[8192];
    __shared__ __align__(16) unsigned char Vt[8192];
    __shared__ __align__(16) unsigned char Pl[4][2048];
    __shared__ float Ol[4][16][65];

    int qi = start + z * 64 + wave * 16 + lq;
    int qic = min(qi, end - 1);
    const float* qp = qkv + (size_t)qic * 768 + qoff + lk * 8;
    short8 qf[2];
    #pragma unroll
    for (int ks = 0; ks < 2; ++ks) {
        float4 a = *(const float4*)(qp + ks * 32);
        float4 b = *(const float4*)(qp + ks * 32 + 4);
        qf[ks] = pack8(a, b, 0.125f);
    }

    float m = -1e30f, l = 0.f;
    f32x4 acc[4] = {};

    int ntile = (S + 63) >> 6;
    for (int tile = 0; tile < ntile; ++tile) {
        int jcnt = S - tile * 64; if (jcnt > 64) jcnt = 64;
        {
            int j = t >> 2, d0 = (t & 3) * 16;
            unsigned char* krow = Kl + j * 128;
            if (j < jcnt) {
                const float* kp = qkv + (size_t)(start + tile * 64 + j) * 768 + 256 + qoff + d0;
                float4 k0 = *(const float4*)kp, k1 = *(const float4*)(kp + 4);
                float4 k2 = *(const float4*)(kp + 8), k3 = *(const float4*)(kp + 12);
                uint4 pc0 = { pk2(k0.x, k0.y), pk2(k0.z, k0.w), pk2(k1.x, k1.y), pk2(k1.z, k1.w) };
                uint4 pc1 = { pk2(k2.x, k2.y), pk2(k2.z, k2.w), pk2(k3.x, k3.y), pk2(k3.z, k3.w) };
                *(uint4*)(krow + ((d0 * 2) ^ ((j & 7) << 4))) = pc0;
                *(uint4*)(krow + ((d0 * 2 + 16) ^ ((j & 7) << 4))) = pc1;
                const float* vp = kp + 256;
                float4 v0 = *(const float4*)vp, v1 = *(const float4*)(vp + 4);
                float4 v2 = *(const float4*)(vp + 8), v3 = *(const float4*)(vp + 12);
                float vv[16] = { v0.x, v0.y, v0.z, v0.w, v1.x, v1.y, v1.z, v1.w,
                                 v2.x, v2.y, v2.z, v2.w, v3.x, v3.y, v3.z, v3.w };
                #pragma unroll
                for (int i = 0; i < 16; ++i) {
                    int d = d0 + i;
                    *(unsigned short*)(Vt + d * 128 + ((j * 2) ^ ((d & 7) << 4))) = f2bf(vv[i]);
                }
            } else {
                uint4 zz = { 0, 0, 0, 0 };
                *(uint4*)(krow + ((d0 * 2) ^ ((j & 7) << 4))) = zz;
                *(uint4*)(krow + ((d0 * 2 + 16) ^ ((j & 7) << 4))) = zz;
                #pragma unroll
                for (int i = 0; i < 16; ++i) {
                    int d = d0 + i;
                    *(unsigned short*)(Vt + d * 128 + ((j * 2) ^ ((d & 7) << 4))) = 0;
                }
            }
        }
        __syncthreads();

        f32x4 sv[4];
        #pragma unroll
        for (int kt = 0; kt < 4; ++kt) {
            int kr = kt * 16 + lq;
            f32x4 s = {};
            #pragma unroll
            for (int ks = 0; ks < 2; ++ks) {
                short8 kf = *(const short8*)(Kl + kr * 128 + ((ks * 64 + lk * 16) ^ ((kr & 7) << 4)));
                s = __builtin_amdgcn_mfma_f32_16x16x32_bf16(kf, qf[ks], s, 0, 0, 0);
            }
            sv[kt] = s;
        }
        float pm = -1e30f;
        #pragma unroll
        for (int kt = 0; kt < 4; ++kt) {
            #pragma unroll
            for (int r = 0; r < 4; ++r) {
                int kk = tile * 64 + kt * 16 + lk * 4 + r;
                float s = (kk < S) ? sv[kt][r] : -1e30f;
                sv[kt][r] = s;
                pm = fmaxf(pm, s);
            }
        }
        pm = fmaxf(pm, __shfl_xor(pm, 16));
        pm = fmaxf(pm, __shfl_xor(pm, 32));
        float mn = fmaxf(m, pm);
        float corr = __expf(m - mn);
        m = mn;
        float ps = 0.f;
        #pragma unroll
        for (int kt = 0; kt < 4; ++kt) {
            #pragma unroll
            for (int r = 0; r < 4; ++r) {
                float p = __expf(sv[kt][r] - mn);
                sv[kt][r] = p;
                ps += p;
            }
            uint2 w = { pk2(sv[kt][0], sv[kt][1]), pk2(sv[kt][2], sv[kt][3]) };
            *(uint2*)(Pl[wave] + lq * 128 + ((kt * 32 + lk * 8) ^ ((lq & 7) << 4))) = w;
        }
        ps += __shfl_xor(ps, 16);
        ps += __shfl_xor(ps, 32);
        l = l * corr + ps;
        #pragma unroll
        for (int dt = 0; dt < 4; ++dt) {
            #pragma unroll
            for (int r = 0; r < 4; ++r) acc[dt][r] *= corr;
        }
        #pragma unroll
        for (int ks = 0; ks < 2; ++ks) {
            short8 pf = *(const short8*)(Pl[wave] + lq * 128 + ((ks * 64 + lk * 16) ^ ((lq & 7) << 4)));
            #pragma unroll
            for (int dt = 0; dt < 4; ++dt) {
                int dr = dt * 16 + lq;
                short8 vf = *(const short8*)(Vt + dr * 128 + ((ks * 64 + lk * 16) ^ ((dr & 7) << 4)));
                acc[dt] = __builtin_amdgcn_mfma_f32_16x16x32_bf16(vf, pf, acc[dt], 0, 0, 0);
            }
        }
        __syncthreads();
    }

    float linv = 1.0f / l;
    #pragma unroll
    for (int dt = 0; dt < 4; ++dt) {
        #pragma unroll
        for (int r = 0; r < 4; ++r)
            Ol[wave][lq][dt * 16 + lk * 4 + r] = acc[dt][r] * linv;
    }
    int q2 = lane >> 2, c2 = lane & 3;
    int qg = start + z * 64 + wave * 16 + q2;
    if (qg < end) {
        float* op = o + (size_t)qg * DD + qoff + c2 * 16;
        const float* sp = &Ol[wave][q2][c2 * 16];
        #pragma unroll
        for (int i = 0; i < 4; ++i) ((float4*)op)[i] = *(const float4*)(sp + i * 4);
    }
}

// ---------------- classifier: wave per row ----------------
__global__ void aml_cls_k(const float* __restrict__ h, const float* __restrict__ w,
                          const float* __restrict__ b, float* __restrict__ out) {
    int row = blockIdx.x * 4 + (threadIdx.x >> 6);
    int lane = threadIdx.x & 63;
    float4 v = *(const float4*)(h + (size_t)row * DD + lane * 4);
    float4 w0 = *(const float4*)(w + lane * 4);
    float4 w1 = *(const float4*)(w + DD + lane * 4);
    float a0 = v.x * w0.x + v.y * w0.y + v.z * w0.z + v.w * w0.w;
    float a1 = v.x * w1.x + v.y * w1.y + v.z * w1.z + v.w * w1.w;
    #pragma unroll
    for (int off = 32; off; off >>= 1) {
        a0 += __shfl_xor(a0, off);
        a1 += __shfl_xor(a1, off);
    }
    if (lane == 0) {
        out[row * 2]     = a0 + b[0];
        out[row * 2 + 1] = a1 + b[1];
    }
}

extern "C" void kernel_launch(void* const* d_in, const int* in_sizes, int n_in,
                              void* d_out, int out_size, void* d_ws, size_t ws_size,
                              hipStream_t stream) {
    const float* x       = (const float*)d_in[0];
    const int*   ei      = (const int*)d_in[1];
    const int*   ts      = (const int*)d_in[2];
    const float* lin_l_w = (const float*)d_in[3];
    const float* lin_l_b = (const float*)d_in[4];
    const float* lin_r_w = (const float*)d_in[5];
    const float* bn_g    = (const float*)d_in[6];
    const float* bn_b    = (const float*)d_in[7];
    const float* inp_w   = (const float*)d_in[8];
    const float* inp_b   = (const float*)d_in[9];
    const float* out_w   = (const float*)d_in[10];
    const float* out_b   = (const float*)d_in[11];
    const float* ff1_w   = (const float*)d_in[12];
    const float* ff1_b   = (const float*)d_in[13];
    const float* ff2_w   = (const float*)d_in[14];
    const float* ff2_b   = (const float*)d_in[15];
    const float* ln1_g   = (const float*)d_in[16];
    const float* ln1_b   = (const float*)d_in[17];
    const float* ln2_g   = (const float*)d_in[18];
    const float* ln2_b   = (const float*)d_in[19];
    const float* cls_w   = (const float*)d_in[20];
    const float* cls_b   = (const float*)d_in[21];

    float* ws     = (float*)d_ws;
    float* stats  = ws;                          // 512 f32 (zeroed)
    int*   deg    = (int*)(stats + 512);         // NN (zeroed)
    int*   rowptr = deg + NN;                    // NN+4 (padded, keeps 16B alignment)
    int*   cursor = rowptr + NN + 4;             // NN
    int*   eid    = cursor + NN;                 // EE
    int*   offs   = eid + EE;                    // 64
    unsigned short* wb = (unsigned short*)(offs + 64);  // WROWS*256 bf16
    float* h      = (float*)(wb + (size_t)WROWS * 256); // N*256
    float* qkv    = h + (size_t)NN * DD;         // N*768
    float* t1     = qkv + (size_t)NN * 768;      // N*256
    float* ac     = qkv;                         // alias (consumed before qkv written)

    const unsigned short* wb_cat = wb;
    const unsigned short* wb_inp[2] = { wb + (size_t)(256) * 256,
                                        wb + (size_t)(256 + 1536) * 256 };
    const unsigned short* wb_out[2] = { wb + (size_t)(256 + 768) * 256,
                                        wb + (size_t)(256 + 1536 + 768) * 256 };
    const unsigned short* wb_ff1[2] = { wb + (size_t)(256 + 1024) * 256,
                                        wb + (size_t)(256 + 1536 + 1024) * 256 };
    const unsigned short* wb_ff2[2] = { wb + (size_t)(256 + 1280) * 256,
                                        wb + (size_t)(256 + 1536 + 1280) * 256 };

    hipMemsetAsync(stats, 0, 512 * sizeof(float) + NN * sizeof(int), stream);

    aml_hist_k<<<EE / 256, 256, 0, stream>>>(ei, deg);
    aml_scan_k<<<1, 256, 0, stream>>>(deg, rowptr, cursor);
    aml_scatter2_k<<<EE / 256, 256, 0, stream>>>(ei, cursor, eid);
    aml_gather_k<<<NN / 4, 256, 0, stream>>>(x, rowptr, eid, ac);
    aml_prep_k<<<WROWS + 1, 256, 0, stream>>>(lin_l_w, lin_r_w, inp_w, out_w, ff1_w, ff2_w,
                                              ts, wb, offs);
    aml_gemm3_k<0><<<dim3(NN / 16, 1), 256, 0, stream>>>(ac, wb_cat, lin_l_b, h, DD, nullptr, nullptr);
    aml_bn_stats_k<<<64, 256, 0, stream>>>(h, stats);
    aml_bn_apply_k<<<(NN * DD) / 256, 256, 0, stream>>>(h, stats, bn_g, bn_b);

    for (int l = 0; l < 2; ++l) {
        aml_gemm3_k<0><<<dim3(NN / 16, 3), 256, 0, stream>>>(h, wb_inp[l], inp_b + (size_t)l * 768,
                                                             qkv, 768, nullptr, nullptr);
        aml_attn_k<<<dim3(TT, NH, ATTN_Z), 256, 0, stream>>>(qkv, offs, t1);
        aml_gemm3_k<2><<<dim3(NN / 16, 1), 256, 0, stream>>>(t1, wb_out[l], out_b + (size_t)l * DD,
                                                             h, DD, ln1_g + (size_t)l * DD,
                                                             ln1_b + (size_t)l * DD);
        aml_gemm3_k<1><<<dim3(NN / 16, 1), 256, 0, stream>>>(h, wb_ff1[l], ff1_b + (size_t)l * DD,
                                                             t1, DD, nullptr, nullptr);
        aml_gemm3_k<2><<<dim3(NN / 16, 1), 256, 0, stream>>>(t1, wb_ff2[l], ff2_b + (size_t)l * DD,
                                                             h, DD, ln2_g + (size_t)l * DD,
                                                             ln2_b + (size_t)l * DD);
    }

    aml_cls_k<<<NN / 4, 256, 0, stream>>>(h, cls_w, cls_b, (float*)d_out);
}

// Round 8
// 163.632 us; speedup vs baseline: 1.9385x; 1.5735x over previous
//
#include <hip/hip_runtime.h>

#define NN   6144
#define EE   98304
#define DIN  128
#define DD   256
#define TT   32
#define NH   4
#define ATTN_Z 6
#define WROWS 3328   // 256 wcat + 2*(768+256+256+256)

typedef __attribute__((ext_vector_type(8))) short short8;
typedef __attribute__((ext_vector_type(4))) float f32x4;
typedef unsigned short u16;

__device__ __forceinline__ float bf2f(u16 u) {
    return __uint_as_float(((unsigned)u) << 16);
}
__device__ __forceinline__ u16 f2bf(float f) {
    unsigned u = __float_as_uint(f);
    return (u16)((u + 0x7fffu + ((u >> 16) & 1u)) >> 16);
}
__device__ __forceinline__ unsigned pk2(float a, float b) {
    return (unsigned)f2bf(a) | ((unsigned)f2bf(b) << 16);
}

// ---------------- CSR build: histogram ----------------
__global__ void aml_hist_k(const int* __restrict__ ei, int* __restrict__ deg) {
    int e = blockIdx.x * 256 + threadIdx.x;
    if (e < EE) atomicAdd(&deg[ei[EE + e]], 1);
}

// ---------------- CSR build: exclusive scan ----------------
__global__ void aml_scan_k(const int* __restrict__ deg, int* __restrict__ rowptr,
                           int* __restrict__ cursor) {
    int t = threadIdx.x;
    int base = t * 24;
    int loc[24];
    int s = 0;
    #pragma unroll
    for (int j = 0; j < 24; ++j) { loc[j] = s; s += deg[base + j]; }
    __shared__ int part[256];
    part[t] = s;
    __syncthreads();
    for (int o = 1; o < 256; o <<= 1) {
        int v = (t >= o) ? part[t - o] : 0;
        __syncthreads();
        part[t] += v;
        __syncthreads();
    }
    int off = (t > 0) ? part[t - 1] : 0;
    #pragma unroll
    for (int j = 0; j < 24; ++j) {
        rowptr[base + j] = off + loc[j];
        cursor[base + j] = off + loc[j];
    }
    if (t == 255) rowptr[NN] = part[255];
}

// ---------------- CSR build: scatter edge sources ----------------
__global__ void aml_scatter2_k(const int* __restrict__ ei, int* __restrict__ cursor,
                               int* __restrict__ eid) {
    int e = blockIdx.x * 256 + threadIdx.x;
    if (e >= EE) return;
    int slot = atomicAdd(&cursor[ei[EE + e]], 1);
    eid[slot] = ei[e];
}

// ---------------- gather-mean + concat -> bf16 ac ----------------
__global__ void aml_gather_k(const float* __restrict__ x, const int* __restrict__ rowptr,
                             const int* __restrict__ eid, u16* __restrict__ ac) {
    int node = blockIdx.x * 4 + (threadIdx.x >> 6);
    int lane = threadIdx.x & 63;
    int p0 = rowptr[node], p1 = rowptr[node + 1];
    float ax = 0.f, ay = 0.f;
    int j = p0;
    for (; j + 1 < p1; j += 2) {
        int s0 = eid[j], s1 = eid[j + 1];
        float2 v0 = *(const float2*)(x + (size_t)s0 * DIN + lane * 2);
        float2 v1 = *(const float2*)(x + (size_t)s1 * DIN + lane * 2);
        ax += v0.x + v1.x; ay += v0.y + v1.y;
    }
    if (j < p1) {
        float2 v = *(const float2*)(x + (size_t)eid[j] * DIN + lane * 2);
        ax += v.x; ay += v.y;
    }
    float inv = 1.0f / fmaxf((float)(p1 - p0), 1.0f);
    float2 xr = *(const float2*)(x + (size_t)node * DIN + lane * 2);
    *(unsigned*)(ac + (size_t)node * DD + lane * 2) = pk2(ax * inv, ay * inv);
    *(unsigned*)(ac + (size_t)node * DD + DIN + lane * 2) = pk2(xr.x, xr.y);
}

// ---------------- prep: all weights -> bf16 rows [WROWS][256]; + segment offsets ----------------
__global__ void aml_prep_k(const float* __restrict__ lin_l_w, const float* __restrict__ lin_r_w,
                           const float* __restrict__ inp_w, const float* __restrict__ out_w,
                           const float* __restrict__ ff1_w, const float* __restrict__ ff2_w,
                           const int* __restrict__ ts, u16* __restrict__ wb,
                           int* __restrict__ offs) {
    int r = blockIdx.x;
    if (r == WROWS) {
        int t = threadIdx.x;
        if (t <= TT) {
            int lo = 0, hi = NN;
            while (lo < hi) { int mid = (lo + hi) >> 1; if (ts[mid] < t) lo = mid + 1; else hi = mid; }
            offs[t] = lo;
        }
        return;
    }
    int k = threadIdx.x;
    float v;
    if (r < 256) {
        v = (k < DIN) ? lin_l_w[r * DIN + k] : lin_r_w[r * DIN + (k - DIN)];
    } else {
        int r2 = r - 256;
        int l = r2 / 1536, r3 = r2 % 1536;
        const float* src; int rr;
        if (r3 < 768)       { src = inp_w + (size_t)l * 768 * DD; rr = r3; }
        else if (r3 < 1024) { src = out_w + (size_t)l * DD * DD;  rr = r3 - 768; }
        else if (r3 < 1280) { src = ff1_w + (size_t)l * DD * DD;  rr = r3 - 1024; }
        else                { src = ff2_w + (size_t)l * DD * DD;  rr = r3 - 1280; }
        v = src[(size_t)rr * DD + k];
    }
    wb[(size_t)r * DD + k] = f2bf(v);
}

// ---------------- MFMA GEMM (R5 structure): 64x64 tile, 4 waves, LDS-staged ----------------
// AF32: A is f32 (pk2 staging) else bf16 (copy). CF32: output f32 else bf16. RELU on output.
template <int RELU, int AF32, int CF32>
__global__ __launch_bounds__(256)
void aml_gemm_k(const void* __restrict__ A, const u16* __restrict__ Wb,
                const float* __restrict__ bias, void* __restrict__ C, int M) {
    __shared__ __align__(16) unsigned char lds[65536];
    const int t = threadIdx.x;
    const int brow = blockIdx.x * 64;
    const int bcol = blockIdx.y * 64;

    const u16* srcW = Wb + (size_t)bcol * 256;
    #pragma unroll
    for (int p = 0; p < 8; ++p) {
        int c = t + p * 256;
        int row = c >> 5;
        int colb = (c & 31) * 16;
        int dst = row * 512 + (colb ^ ((row & 7) << 4));
        if (AF32) {
            const float* sA = (const float*)A + (size_t)(brow + row) * 256 + (c & 31) * 8;
            float4 a0 = *(const float4*)sA;
            float4 a1 = *(const float4*)(sA + 4);
            uint4 pa = { pk2(a0.x, a0.y), pk2(a0.z, a0.w), pk2(a1.x, a1.y), pk2(a1.z, a1.w) };
            *(uint4*)(lds + dst) = pa;
        } else {
            const u16* sA = (const u16*)A + (size_t)(brow + row) * 256 + (c & 31) * 8;
            *(uint4*)(lds + dst) = *(const uint4*)sA;
        }
        *(uint4*)(lds + 32768 + dst) = *(const uint4*)(srcW + (size_t)row * 256 + (c & 31) * 8);
    }
    __syncthreads();

    const int wave = t >> 6, lane = t & 63;
    const int lrow = lane & 15, lk = lane >> 4;
    const int arow = wave * 16 + lrow;
    f32x4 acc[4] = {};
    #pragma unroll
    for (int ks = 0; ks < 8; ++ks) {
        int kbyte = ks * 64 + lk * 16;
        short8 af = *(const short8*)(lds + arow * 512 + (kbyte ^ ((arow & 7) << 4)));
        #pragma unroll
        for (int ct = 0; ct < 4; ++ct) {
            int wrow = ct * 16 + lrow;
            short8 bf = *(const short8*)(lds + 32768 + wrow * 512 + (kbyte ^ ((wrow & 7) << 4)));
            acc[ct] = __builtin_amdgcn_mfma_f32_16x16x32_bf16(af, bf, acc[ct], 0, 0, 0);
        }
    }

    #pragma unroll
    for (int ct = 0; ct < 4; ++ct) {
        int col = bcol + ct * 16 + lrow;
        float bv = bias[col];
        #pragma unroll
        for (int r = 0; r < 4; ++r) {
            int grow = brow + wave * 16 + lk * 4 + r;
            float v = acc[ct][r] + bv;
            if (RELU) v = fmaxf(v, 0.0f);
            if (CF32) ((float*)C)[(size_t)grow * M + col] = v;
            else      ((u16*)C)[(size_t)grow * M + col] = f2bf(v);
        }
    }
}

// ---------------- BatchNorm stats (h f32) ----------------
__global__ void aml_bn_stats_k(const float* __restrict__ h, float* __restrict__ stats) {
    int d = threadIdx.x;
    int r0 = blockIdx.x * 96;
    float s = 0.f, ss = 0.f;
    for (int i = 0; i < 96; ++i) {
        float v = h[(size_t)(r0 + i) * DD + d];
        s += v; ss += v * v;
    }
    atomicAdd(&stats[d], s);
    atomicAdd(&stats[DD + d], ss);
}

__global__ void aml_bn_apply_k(float* __restrict__ h, const float* __restrict__ stats,
                               const float* __restrict__ g, const float* __restrict__ b) {
    int idx = blockIdx.x * 256 + threadIdx.x;
    int d = idx & (DD - 1);
    float mu = stats[d] * (1.0f / NN);
    float var = stats[DD + d] * (1.0f / NN) - mu * mu;
    float v = (h[idx] - mu) * rsqrtf(var + 1e-5f) * g[d] + b[d];
    h[idx] = fmaxf(v, 0.0f);
}

// ---------------- MFMA flash attention (bf16 qkv in, bf16 out) ----------------
__global__ __launch_bounds__(256)
void aml_attn_k(const u16* __restrict__ qkv, const int* __restrict__ offs,
                u16* __restrict__ o) {
    int tb = blockIdx.x, head = blockIdx.y, z = blockIdx.z;
    int start = offs[tb], end = offs[tb + 1];
    int S = end - start;
    if (S <= z * 64) return;
    int t = threadIdx.x, wave = t >> 6, lane = t & 63;
    int lq = lane & 15, lk = lane >> 4;
    int qoff = head * 64;

    __shared__ __align__(16) unsigned char Kl[8192];     // [64k][64d] bf16, swizzled
    __shared__ __align__(16) unsigned char Vt[8192];     // [64d][64k] bf16, swizzled
    __shared__ __align__(16) unsigned char Pl[4][2048];  // per-wave [16q][64k] bf16, swizzled
    __shared__ float Ol[4][16][65];

    int qi = start + z * 64 + wave * 16 + lq;
    int qic = min(qi, end - 1);
    const u16* qp = qkv + (size_t)qic * 768 + qoff + lk * 8;
    short8 qf[2];
    qf[0] = *(const short8*)qp;
    qf[1] = *(const short8*)(qp + 32);

    float m = -1e30f, l = 0.f;
    f32x4 acc[4] = {};

    int ntile = (S + 63) >> 6;
    for (int tile = 0; tile < ntile; ++tile) {
        int jcnt = S - tile * 64; if (jcnt > 64) jcnt = 64;
        {
            int j = t >> 2, d0 = (t & 3) * 16;
            unsigned char* krow = Kl + j * 128;
            if (j < jcnt) {
                const u16* kp = qkv + (size_t)(start + tile * 64 + j) * 768 + 256 + qoff + d0;
                *(uint4*)(krow + ((d0 * 2) ^ ((j & 7) << 4))) = *(const uint4*)kp;
                *(uint4*)(krow + ((d0 * 2 + 16) ^ ((j & 7) << 4))) = *(const uint4*)(kp + 8);
                const u16* vp = kp + 256;
                #pragma unroll
                for (int i = 0; i < 16; ++i) {
                    int d = d0 + i;
                    *(u16*)(Vt + d * 128 + ((j * 2) ^ ((d & 7) << 4))) = vp[i];
                }
            } else {
                uint4 zz = { 0, 0, 0, 0 };
                *(uint4*)(krow + ((d0 * 2) ^ ((j & 7) << 4))) = zz;
                *(uint4*)(krow + ((d0 * 2 + 16) ^ ((j & 7) << 4))) = zz;
                #pragma unroll
                for (int i = 0; i < 16; ++i) {
                    int d = d0 + i;
                    *(u16*)(Vt + d * 128 + ((j * 2) ^ ((d & 7) << 4))) = 0;
                }
            }
        }
        __syncthreads();

        f32x4 sv[4];
        #pragma unroll
        for (int kt = 0; kt < 4; ++kt) {
            int kr = kt * 16 + lq;
            f32x4 s = {};
            #pragma unroll
            for (int ks = 0; ks < 2; ++ks) {
                short8 kf = *(const short8*)(Kl + kr * 128 + ((ks * 64 + lk * 16) ^ ((kr & 7) << 4)));
                s = __builtin_amdgcn_mfma_f32_16x16x32_bf16(kf, qf[ks], s, 0, 0, 0);
            }
            sv[kt] = s;
        }
        float pm = -1e30f;
        #pragma unroll
        for (int kt = 0; kt < 4; ++kt) {
            #pragma unroll
            for (int r = 0; r < 4; ++r) {
                int kk = tile * 64 + kt * 16 + lk * 4 + r;
                float s = (kk < S) ? sv[kt][r] * 0.125f : -1e30f;
                sv[kt][r] = s;
                pm = fmaxf(pm, s);
            }
        }
        pm = fmaxf(pm, __shfl_xor(pm, 16));
        pm = fmaxf(pm, __shfl_xor(pm, 32));
        float mn = fmaxf(m, pm);
        float corr = __expf(m - mn);
        m = mn;
        float ps = 0.f;
        #pragma unroll
        for (int kt = 0; kt < 4; ++kt) {
            #pragma unroll
            for (int r = 0; r < 4; ++r) {
                float p = __expf(sv[kt][r] - mn);
                sv[kt][r] = p;
                ps += p;
            }
            uint2 w = { pk2(sv[kt][0], sv[kt][1]), pk2(sv[kt][2], sv[kt][3]) };
            *(uint2*)(Pl[wave] + lq * 128 + ((kt * 32 + lk * 8) ^ ((lq & 7) << 4))) = w;
        }
        ps += __shfl_xor(ps, 16);
        ps += __shfl_xor(ps, 32);
        l = l * corr + ps;
        #pragma unroll
        for (int dt = 0; dt < 4; ++dt) {
            #pragma unroll
            for (int r = 0; r < 4; ++r) acc[dt][r] *= corr;
        }
        #pragma unroll
        for (int ks = 0; ks < 2; ++ks) {
            short8 pf = *(const short8*)(Pl[wave] + lq * 128 + ((ks * 64 + lk * 16) ^ ((lq & 7) << 4)));
            #pragma unroll
            for (int dt = 0; dt < 4; ++dt) {
                int dr = dt * 16 + lq;
                short8 vf = *(const short8*)(Vt + dr * 128 + ((ks * 64 + lk * 16) ^ ((dr & 7) << 4)));
                acc[dt] = __builtin_amdgcn_mfma_f32_16x16x32_bf16(vf, pf, acc[dt], 0, 0, 0);
            }
        }
        __syncthreads();
    }

    float linv = 1.0f / l;
    #pragma unroll
    for (int dt = 0; dt < 4; ++dt) {
        #pragma unroll
        for (int r = 0; r < 4; ++r)
            Ol[wave][lq][dt * 16 + lk * 4 + r] = acc[dt][r] * linv;
    }
    int q2 = lane >> 2, c2 = lane & 3;
    int qg = start + z * 64 + wave * 16 + q2;
    if (qg < end) {
        u16* op = o + (size_t)qg * DD + qoff + c2 * 16;
        const float* sp = &Ol[wave][q2][c2 * 16];
        #pragma unroll
        for (int i = 0; i < 8; ++i)
            ((unsigned*)op)[i] = pk2(sp[2 * i], sp[2 * i + 1]);
    }
}

// ---------------- residual + LayerNorm: h(f32) += r(bf16), normalize ----------------
__global__ void aml_ln_k(float* __restrict__ h, const u16* __restrict__ r,
                         const float* __restrict__ g, const float* __restrict__ b) {
    int row = blockIdx.x * 4 + (threadIdx.x >> 6);
    int lane = threadIdx.x & 63;
    float* hp = h + (size_t)row * DD + lane * 4;
    float4 v = *(const float4*)hp;
    uint2 rv = *(const uint2*)(r + (size_t)row * DD + lane * 4);
    v.x += bf2f((u16)(rv.x & 0xffff));
    v.y += bf2f((u16)(rv.x >> 16));
    v.z += bf2f((u16)(rv.y & 0xffff));
    v.w += bf2f((u16)(rv.y >> 16));
    float s = v.x + v.y + v.z + v.w;
    float ss = v.x * v.x + v.y * v.y + v.z * v.z + v.w * v.w;
    #pragma unroll
    for (int off = 32; off; off >>= 1) {
        s += __shfl_xor(s, off);
        ss += __shfl_xor(ss, off);
    }
    float mu = s * (1.0f / DD);
    float var = ss * (1.0f / DD) - mu * mu;
    float inv = rsqrtf(var + 1e-5f);
    float4 gv = *(const float4*)(g + lane * 4);
    float4 bv = *(const float4*)(b + lane * 4);
    v.x = (v.x - mu) * inv * gv.x + bv.x;
    v.y = (v.y - mu) * inv * gv.y + bv.y;
    v.z = (v.z - mu) * inv * gv.z + bv.z;
    v.w = (v.w - mu) * inv * gv.w + bv.w;
    *(float4*)hp = v;
}

// ---------------- classifier (h f32) ----------------
__global__ void aml_cls_k(const float* __restrict__ h, const float* __restrict__ w,
                          const float* __restrict__ b, float* __restrict__ out) {
    int row = blockIdx.x * 4 + (threadIdx.x >> 6);
    int lane = threadIdx.x & 63;
    float4 v = *(const float4*)(h + (size_t)row * DD + lane * 4);
    float4 w0 = *(const float4*)(w + lane * 4);
    float4 w1 = *(const float4*)(w + DD + lane * 4);
    float a0 = v.x * w0.x + v.y * w0.y + v.z * w0.z + v.w * w0.w;
    float a1 = v.x * w1.x + v.y * w1.y + v.z * w1.z + v.w * w1.w;
    #pragma unroll
    for (int off = 32; off; off >>= 1) {
        a0 += __shfl_xor(a0, off);
        a1 += __shfl_xor(a1, off);
    }
    if (lane == 0) {
        out[row * 2]     = a0 + b[0];
        out[row * 2 + 1] = a1 + b[1];
    }
}

extern "C" void kernel_launch(void* const* d_in, const int* in_sizes, int n_in,
                              void* d_out, int out_size, void* d_ws, size_t ws_size,
                              hipStream_t stream) {
    const float* x       = (const float*)d_in[0];
    const int*   ei      = (const int*)d_in[1];
    const int*   ts      = (const int*)d_in[2];
    const float* lin_l_w = (const float*)d_in[3];
    const float* lin_l_b = (const float*)d_in[4];
    const float* lin_r_w = (const float*)d_in[5];
    const float* bn_g    = (const float*)d_in[6];
    const float* bn_b    = (const float*)d_in[7];
    const float* inp_w   = (const float*)d_in[8];
    const float* inp_b   = (const float*)d_in[9];
    const float* out_w   = (const float*)d_in[10];
    const float* out_b   = (const float*)d_in[11];
    const float* ff1_w   = (const float*)d_in[12];
    const float* ff1_b   = (const float*)d_in[13];
    const float* ff2_w   = (const float*)d_in[14];
    const float* ff2_b   = (const float*)d_in[15];
    const float* ln1_g   = (const float*)d_in[16];
    const float* ln1_b   = (const float*)d_in[17];
    const float* ln2_g   = (const float*)d_in[18];
    const float* ln2_b   = (const float*)d_in[19];
    const float* cls_w   = (const float*)d_in[20];
    const float* cls_b   = (const float*)d_in[21];

    float* ws     = (float*)d_ws;
    float* stats  = ws;                          // 512 f32 (zeroed)
    int*   deg    = (int*)(stats + 512);         // NN (zeroed)
    int*   rowptr = deg + NN;                    // NN+4 (padded)
    int*   cursor = rowptr + NN + 4;             // NN
    int*   eid    = cursor + NN;                 // EE
    int*   offs   = eid + EE;                    // 64
    u16*   wb     = (u16*)(offs + 64);           // WROWS*256 bf16
    float* h      = (float*)(wb + (size_t)WROWS * 256);  // N*256 f32
    u16*   qkv    = (u16*)(h + (size_t)NN * DD); // N*768 bf16
    u16*   t1     = qkv + (size_t)NN * 768;      // N*256 bf16
    u16*   t2     = t1 + (size_t)NN * DD;        // N*256 bf16
    u16*   ac     = qkv;                         // alias (consumed before qkv written)

    const u16* wb_cat = wb;
    const u16* wb_inp[2] = { wb + (size_t)(256) * 256,        wb + (size_t)(256 + 1536) * 256 };
    const u16* wb_out[2] = { wb + (size_t)(256 + 768) * 256,  wb + (size_t)(256 + 1536 + 768) * 256 };
    const u16* wb_ff1[2] = { wb + (size_t)(256 + 1024) * 256, wb + (size_t)(256 + 1536 + 1024) * 256 };
    const u16* wb_ff2[2] = { wb + (size_t)(256 + 1280) * 256, wb + (size_t)(256 + 1536 + 1280) * 256 };

    hipMemsetAsync(stats, 0, 512 * sizeof(float) + NN * sizeof(int), stream);

    aml_hist_k<<<EE / 256, 256, 0, stream>>>(ei, deg);
    aml_scan_k<<<1, 256, 0, stream>>>(deg, rowptr, cursor);
    aml_scatter2_k<<<EE / 256, 256, 0, stream>>>(ei, cursor, eid);
    aml_gather_k<<<NN / 4, 256, 0, stream>>>(x, rowptr, eid, ac);
    aml_prep_k<<<WROWS + 1, 256, 0, stream>>>(lin_l_w, lin_r_w, inp_w, out_w, ff1_w, ff2_w,
                                              ts, wb, offs);
    // SAGE: ac(bf16) x wcat -> h(f32)
    aml_gemm_k<0, 0, 1><<<dim3(NN / 64, 4), 256, 0, stream>>>(ac, wb_cat, lin_l_b, h, DD);
    aml_bn_stats_k<<<64, 256, 0, stream>>>(h, stats);
    aml_bn_apply_k<<<(NN * DD) / 256, 256, 0, stream>>>(h, stats, bn_g, bn_b);

    for (int l = 0; l < 2; ++l) {
        // qkv: h(f32) x inp_w -> qkv(bf16)
        aml_gemm_k<0, 1, 0><<<dim3(NN / 64, 12), 256, 0, stream>>>(h, wb_inp[l],
                                                                   inp_b + (size_t)l * 768, qkv, 768);
        aml_attn_k<<<dim3(TT, NH, ATTN_Z), 256, 0, stream>>>(qkv, offs, t1);
        // out-proj: t1(bf16) x out_w -> t2(bf16)
        aml_gemm_k<0, 0, 0><<<dim3(NN / 64, 4), 256, 0, stream>>>(t1, wb_out[l],
                                                                  out_b + (size_t)l * DD, t2, DD);
        aml_ln_k<<<NN / 4, 256, 0, stream>>>(h, t2, ln1_g + (size_t)l * DD, ln1_b + (size_t)l * DD);
        // ff1: h(f32) x ff1_w -> t1(bf16), ReLU
        aml_gemm_k<1, 1, 0><<<dim3(NN / 64, 4), 256, 0, stream>>>(h, wb_ff1[l],
                                                                  ff1_b + (size_t)l * DD, t1, DD);
        // ff2: t1(bf16) x ff2_w -> t2(bf16)
        aml_gemm_k<0, 0, 0><<<dim3(NN / 64, 4), 256, 0, stream>>>(t1, wb_ff2[l],
                                                                  ff2_b + (size_t)l * DD, t2, DD);
        aml_ln_k<<<NN / 4, 256, 0, stream>>>(h, t2, ln2_g + (size_t)l * DD, ln2_b + (size_t)l * DD);
    }

    aml_cls_k<<<NN / 4, 256, 0, stream>>>(h, cls_w, cls_b, (float*)d_out);
}